// Round 6
// baseline (3398.339 us; speedup 1.0000x reference)
//
#include <hip/hip_runtime.h>
#include <hip/hip_bf16.h>
#include <math.h>

// ---- Model constants ----
#define BB 16
#define HH 384
#define NHEAD 6
#define DH 64
#define LL 12
#define II 1536
#define NC 1000
#define SS 1025
#define MROWS (BB * SS)      // 16400
#define MPAD  16512          // MROWS padded to multiple of 128
#define KPATCH 768           // 3*16*16
#define MPATCH (BB * 1024)   // 16384
#define QS 1152              // fused qkv row stride
#define SSP 1088             // padded seq stride for V^T (17*64)

typedef __hip_bfloat16 bf16;
typedef __attribute__((ext_vector_type(8))) short bh8;   // 8 bf16 (MFMA A/B frag)
typedef __attribute__((ext_vector_type(4))) float f4x;   // MFMA C/D frag

__device__ __forceinline__ void gload16(const bf16* g, bf16* l) {
    __builtin_amdgcn_global_load_lds(
        (const __attribute__((address_space(1))) unsigned int*)g,
        (__attribute__((address_space(3))) unsigned int*)l, 16, 0, 0);
}

__device__ __forceinline__ unsigned short bf16_bits(float f) {
    __hip_bfloat16 h = __float2bfloat16(f);
    return *reinterpret_cast<unsigned short*>(&h);
}
__device__ __forceinline__ ushort4 pack4_bf16(float a, float b, float c, float d) {
    ushort4 u;
    u.x = bf16_bits(a); u.y = bf16_bits(b); u.z = bf16_bits(c); u.w = bf16_bits(d);
    return u;
}

// ======================= transpose + cast: [L][K][N] f32 -> [L][N][K] bf16 =======================
__global__ __launch_bounds__(256) void transpose_cast_kernel(
    const float* __restrict__ in, bf16* __restrict__ out, int K, int N, int ostride)
{
    __shared__ float tile[32][33];
    int l = blockIdx.z;
    const float* ip = in + (size_t)l * K * N;
    bf16* op = out + (size_t)l * ostride;
    int n0 = blockIdx.x * 32, k0 = blockIdx.y * 32;
    int tx = threadIdx.x & 31, ty = threadIdx.x >> 5;   // 32 x 8
    #pragma unroll
    for (int i = 0; i < 32; i += 8)
        tile[ty + i][tx] = ip[(size_t)(k0 + ty + i) * N + n0 + tx];
    __syncthreads();
    #pragma unroll
    for (int i = 0; i < 32; i += 8)
        op[(size_t)(n0 + ty + i) * K + k0 + tx] = __float2bfloat16(tile[tx][ty + i]);
}

// ======================= plain cast f32 -> bf16 =======================
__global__ __launch_bounds__(256) void cast_kernel(
    const float* __restrict__ in, bf16* __restrict__ out, int n)
{
    int i = blockIdx.x * 1024 + threadIdx.x * 4;
    if (i + 3 < n) {
        float4 v = *(const float4*)&in[i];
        out[i]   = __float2bfloat16(v.x);
        out[i+1] = __float2bfloat16(v.y);
        out[i+2] = __float2bfloat16(v.z);
        out[i+3] = __float2bfloat16(v.w);
    } else {
        for (int j = i; j < n; ++j) out[j] = __float2bfloat16(in[j]);
    }
}

// ======================= concat qkv biases: cb[l][1152] =======================
__global__ __launch_bounds__(384) void bias_concat_kernel(
    const float* __restrict__ bq, const float* __restrict__ bk,
    const float* __restrict__ bv, float* __restrict__ cb)
{
    int l = blockIdx.x, t = threadIdx.x;
    cb[l * QS + t]       = bq[l * HH + t];
    cb[l * QS + 384 + t] = bk[l * HH + t];
    cb[l * QS + 768 + t] = bv[l * HH + t];
}

// ======================= im2row: x[B,3,512,512] -> Pm[16384][768] bf16 =======================
__global__ __launch_bounds__(256) void im2row_kernel(
    const float* __restrict__ x, bf16* __restrict__ Pm)
{
    size_t idx = ((size_t)blockIdx.x * 256 + threadIdx.x) * 8;
    int kk = (int)(idx % KPATCH);
    int m  = (int)(idx / KPATCH);
    int b = m >> 10, p = m & 1023;
    int c = kk >> 8, rem = kk & 255, py = rem >> 4, px = rem & 15;
    int pi = p >> 5, pj = p & 31;
    const float* src = &x[(((size_t)b * 3 + c) * 512 + pi * 16 + py) * 512 + pj * 16 + px];
    float4 a0 = *(const float4*)src;
    float4 a1 = *(const float4*)(src + 4);
    bf16 tmp[8];
    tmp[0] = __float2bfloat16(a0.x); tmp[1] = __float2bfloat16(a0.y);
    tmp[2] = __float2bfloat16(a0.z); tmp[3] = __float2bfloat16(a0.w);
    tmp[4] = __float2bfloat16(a1.x); tmp[5] = __float2bfloat16(a1.y);
    tmp[6] = __float2bfloat16(a1.z); tmp[7] = __float2bfloat16(a1.w);
    *(bh8*)&Pm[idx] = *(bh8*)tmp;
}

// ======================= fill cls rows =======================
__global__ __launch_bounds__(384) void fill_cls_kernel(
    const float* __restrict__ cls, const float* __restrict__ pos, float* __restrict__ h)
{
    h[(size_t)blockIdx.x * SS * HH + threadIdx.x] = cls[threadIdx.x] + pos[threadIdx.x];
}

// ======================= LayerNorm (fp32 in -> bf16 out) =======================
__global__ __launch_bounds__(256) void ln_kernel(
    const float* __restrict__ x, const float* __restrict__ w,
    const float* __restrict__ b, bf16* __restrict__ out, int nrows)
{
    int wave = threadIdx.x >> 6;
    int lane = threadIdx.x & 63;
    int row = blockIdx.x * 4 + wave;
    if (row >= nrows) return;
    const float* xr = x + (size_t)row * HH;
    float vals[6];
    float s = 0.f;
    #pragma unroll
    for (int i = 0; i < 6; ++i) { vals[i] = xr[lane + 64 * i]; s += vals[i]; }
    #pragma unroll
    for (int mask = 32; mask >= 1; mask >>= 1) s += __shfl_xor(s, mask);
    float mean = s * (1.f / HH);
    float vs = 0.f;
    #pragma unroll
    for (int i = 0; i < 6; ++i) { float d = vals[i] - mean; vs += d * d; }
    #pragma unroll
    for (int mask = 32; mask >= 1; mask >>= 1) vs += __shfl_xor(vs, mask);
    float rstd = rsqrtf(vs * (1.f / HH) + 1e-5f);
    bf16* outr = out + (size_t)row * HH;
    #pragma unroll
    for (int i = 0; i < 6; ++i) {
        int jj = lane + 64 * i;
        outr[jj] = __float2bfloat16((vals[i] - mean) * rstd * w[jj] + b[jj]);
    }
}

// ======================= V transpose per layer: qkv v-section -> vt[bh][d][s] =======================
__global__ __launch_bounds__(256) void vt_kernel(
    const bf16* __restrict__ qkv, bf16* __restrict__ vt)
{
    __shared__ bf16 tile[32][33];
    int bh = blockIdx.z;
    int b = bh / NHEAD, hd = bh % NHEAD;
    int s0 = blockIdx.x * 32, d0 = blockIdx.y * 32;
    int tx = threadIdx.x & 31, ty = threadIdx.x >> 5;
    const bf16* src = qkv + ((size_t)b * SS) * QS + 768 + hd * DH;
    #pragma unroll
    for (int i = 0; i < 32; i += 8) {
        int s = s0 + ty + i;
        tile[ty + i][tx] = (s < SS) ? src[(size_t)s * QS + d0 + tx]
                                    : __float2bfloat16(0.f);
    }
    __syncthreads();
    #pragma unroll
    for (int i = 0; i < 32; i += 8)
        vt[((size_t)bh * DH + d0 + ty + i) * SSP + s0 + tx] = tile[tx][ty + i];
}

// ======================= MFMA GEMM (C^T accum, vectorized epilogue) =======================
template<int MODE>
__global__ __launch_bounds__(256) void gemm_v2_kernel(
    const bf16* __restrict__ A, const bf16* __restrict__ Bt,
    const float* __restrict__ bias, const float* __restrict__ res,
    void* __restrict__ out, int M, int N, int K)
{
    __shared__ bf16 As[128 * 64];
    __shared__ bf16 Bs[128 * 64];

    int t = threadIdx.x;
    int w = t >> 6, lane = t & 63;
    int quad = lane >> 4, l15 = lane & 15;
    int bm = blockIdx.x * 128, bn = blockIdx.y * 128;
    int wm = (w >> 1) * 64, wn = (w & 1) * 64;

    int srow = lane >> 3;
    int scol = lane & 7;

    f4x acc[4][4];
    #pragma unroll
    for (int i = 0; i < 4; ++i)
        #pragma unroll
        for (int j = 0; j < 4; ++j) acc[i][j] = 0.f;

    for (int k0 = 0; k0 < K; k0 += 64) {
        #pragma unroll
        for (int p = 0; p < 4; ++p) {
            int c = w * 4 + p;
            int r = c * 8 + srow;
            int gcb = scol ^ (r & 7);
            gload16(A + (size_t)(bm + r) * K + k0 + gcb * 8, &As[c * 8 * 64]);
        }
        #pragma unroll
        for (int p = 0; p < 4; ++p) {
            int c = w * 4 + p;
            int r = c * 8 + srow;
            int gcb = scol ^ (r & 7);
            gload16(Bt + (size_t)(bn + r) * K + k0 + gcb * 8, &Bs[c * 8 * 64]);
        }
        __syncthreads();

        #pragma unroll
        for (int kc = 0; kc < 2; ++kc) {
            bh8 bfr[4];
            #pragma unroll
            for (int nf = 0; nf < 4; ++nf) {
                int rn = wn + nf * 16 + l15;
                int pcb = (kc * 4 + quad) ^ (rn & 7);
                bfr[nf] = *(const bh8*)&Bs[rn * 64 + pcb * 8];
            }
            #pragma unroll
            for (int mf = 0; mf < 4; ++mf) {
                int rm = wm + mf * 16 + l15;
                int pcb = (kc * 4 + quad) ^ (rm & 7);
                bh8 afr = *(const bh8*)&As[rm * 64 + pcb * 8];
                #pragma unroll
                for (int nf = 0; nf < 4; ++nf)
                    acc[mf][nf] = __builtin_amdgcn_mfma_f32_16x16x32_bf16(
                        bfr[nf], afr, acc[mf][nf], 0, 0, 0);
            }
        }
        __syncthreads();
    }

    #pragma unroll
    for (int mf = 0; mf < 4; ++mf) {
        int row = bm + wm + mf * 16 + l15;
        #pragma unroll
        for (int nf = 0; nf < 4; ++nf) {
            f4x v = acc[mf][nf];
            int col0 = bn + wn + nf * 16 + quad * 4;
            float4 b4 = *(const float4*)&bias[col0];
            float vals[4];
            #pragma unroll
            for (int r = 0; r < 4; ++r) vals[r] = v[r] + (&b4.x)[r];
            if (MODE == 0) {
                if (row < M)
                    *(ushort4*)&((bf16*)out)[(size_t)row * N + col0] =
                        pack4_bf16(vals[0], vals[1], vals[2], vals[3]);
            } else if (MODE == 1) {
                #pragma unroll
                for (int r = 0; r < 4; ++r) {
                    float u = vals[r];
                    float z = 0.7978845608028654f * (u + 0.044715f * u * u * u);
                    z = fminf(fmaxf(z, -15.f), 15.f);
                    float e = __expf(2.f * z);
                    vals[r] = 0.5f * u * (1.f + (e - 1.f) / (e + 1.f));
                }
                if (row < M)
                    *(ushort4*)&((bf16*)out)[(size_t)row * N + col0] =
                        pack4_bf16(vals[0], vals[1], vals[2], vals[3]);
            } else if (MODE == 2) {
                if (row < M) {
                    float* o = (float*)out;
                    float4 r4 = *(const float4*)&res[(size_t)row * N + col0];
                    float4 st = {vals[0] + r4.x, vals[1] + r4.y,
                                 vals[2] + r4.z, vals[3] + r4.w};
                    *(float4*)&o[(size_t)row * N + col0] = st;
                }
            } else {  // MODE 3
                int b2 = row >> 10, p2 = row & 1023;
                size_t orow = (size_t)b2 * SS + 1 + p2;
                float4 r4 = *(const float4*)&res[(size_t)(1 + p2) * HH + col0];
                float4 st = {vals[0] + r4.x, vals[1] + r4.y,
                             vals[2] + r4.z, vals[3] + r4.w};
                *(float4*)&((float*)out)[orow * HH + col0] = st;
            }
        }
    }
}

// ======================= Fused MFMA attention v5 =======================
// 128 q-rows/block (2 bands/wave), fixed-shift exp2 softmax, l-sum via
// MFMA ones-row, masking only on the final partial key-tile.
// grid (96, 9): bh fastest for L2 K/V reuse. block 256.
#define PSTR 68   // Ps row stride (elems)

__global__ __launch_bounds__(256) void attn_v5_kernel(
    const bf16* __restrict__ qkv, const bf16* __restrict__ vt,
    bf16* __restrict__ o)
{
    // QPs: Q tile (128x64 = 8192 elems) until frags are extracted, then P
    // scratch (4 waves x 2 bands x 16 rows x PSTR = 8704 elems).
    __shared__ bf16 QPs[8704];
    __shared__ bf16 Ks[64 * 64];
    __shared__ bf16 Vs[80 * 64];   // rows 0-63: V^T; row 64: ones; 65-79: zeros

    int t = threadIdx.x, w = t >> 6, lane = t & 63;
    int quad = lane >> 4, l15 = lane & 15;
    int bh = blockIdx.x;
    int b = bh / NHEAD, hd = bh % NHEAD;
    int q0 = blockIdx.y * 128;
    size_t qbase = ((size_t)b * SS) * QS + hd * DH;
    size_t kbase = qbase + 384;
    size_t vbase = (size_t)bh * DH * SSP;
    size_t obase = ((size_t)b * SS) * HH + hd * DH;

    int srow = lane >> 3, scol = lane & 7;
    int gcb = scol ^ srow;

    // stage Q tile: 128 rows (4 chunks of 8 per wave)
    #pragma unroll
    for (int p = 0; p < 4; ++p) {
        int c = w * 4 + p;
        int r = c * 8 + srow;
        gload16(qkv + qbase + (size_t)(q0 + r) * QS + gcb * 8, &QPs[c * 512]);
    }
    // init Vs ones/zero rows (64..79) — staging never touches them
    for (int i = t; i < 16 * 64; i += 256)
        Vs[64 * 64 + i] = __float2bfloat16(i < 64 ? 1.f : 0.f);
    __syncthreads();

    bh8 qfrag[2][2];
    #pragma unroll
    for (int band = 0; band < 2; ++band) {
        int rm = band * 64 + 16 * w + l15;
        #pragma unroll
        for (int kc = 0; kc < 2; ++kc)
            qfrag[band][kc] = *(const bh8*)&QPs[rm * 64 + ((kc * 4 + quad) ^ (rm & 7)) * 8];
    }

    f4x oacc[2][4];
    f4x oacc_l[2];
    #pragma unroll
    for (int band = 0; band < 2; ++band) {
        oacc_l[band] = 0.f;
        #pragma unroll
        for (int i = 0; i < 4; ++i) oacc[band][i] = 0.f;
    }

    const float C1 = 0.18033688011112042f;  // 0.125 * log2(e)
    const float C2 = -16.0f;                // fixed shift (cancels in normalize)

    for (int c0 = 0; c0 < SS; c0 += 64) {
        __syncthreads();
        #pragma unroll
        for (int p = 0; p < 2; ++p) {
            int c = w * 2 + p;
            int r = c * 8 + srow;
            gload16(qkv + kbase + (size_t)(c0 + r) * QS + gcb * 8, &Ks[c * 512]);
            gload16(vt + vbase + (size_t)r * SSP + c0 + gcb * 8, &Vs[c * 512]);
        }
        __syncthreads();

        bool tail = (c0 + 64 > SS);   // wave-uniform
        #pragma unroll
        for (int band = 0; band < 2; ++band) {
            bf16* Psb = &QPs[((w * 2 + band) * 16) * PSTR];

            // S^T = mfma(K, Q^T); P = exp2(S*C1 + C2)
            #pragma unroll
            for (int nf = 0; nf < 4; ++nf) {
                f4x s = 0.f;
                int rn = nf * 16 + l15;
                #pragma unroll
                for (int kc = 0; kc < 2; ++kc) {
                    bh8 kf = *(const bh8*)&Ks[rn * 64 + ((kc * 4 + quad) ^ (rn & 7)) * 8];
                    s = __builtin_amdgcn_mfma_f32_16x16x32_bf16(kf, qfrag[band][kc], s, 0, 0, 0);
                }
                float pv[4];
                if (tail) {
                    #pragma unroll
                    for (int r = 0; r < 4; ++r) {
                        float p = exp2f(fmaf(s[r], C1, C2));
                        pv[r] = (c0 + nf * 16 + quad * 4 + r < SS) ? p : 0.f;
                    }
                } else {
                    #pragma unroll
                    for (int r = 0; r < 4; ++r)
                        pv[r] = exp2f(fmaf(s[r], C1, C2));
                }
                *(ushort4*)&Psb[l15 * PSTR + nf * 16 + quad * 4] =
                    pack4_bf16(pv[0], pv[1], pv[2], pv[3]);
            }

            bh8 pf[2];
            #pragma unroll
            for (int kc = 0; kc < 2; ++kc)
                pf[kc] = *(const bh8*)&Psb[l15 * PSTR + kc * 32 + quad * 8];

            // O^T += V^T * P^T ; l-row via ones-row tile
            #pragma unroll
            for (int kc = 0; kc < 2; ++kc) {
                #pragma unroll
                for (int nf2 = 0; nf2 < 4; ++nf2) {
                    int rn2 = nf2 * 16 + l15;
                    bh8 vf = *(const bh8*)&Vs[rn2 * 64 + ((kc * 4 + quad) ^ (rn2 & 7)) * 8];
                    oacc[band][nf2] = __builtin_amdgcn_mfma_f32_16x16x32_bf16(
                        vf, pf[kc], oacc[band][nf2], 0, 0, 0);
                }
                bh8 vf1 = *(const bh8*)&Vs[(64 + l15) * 64 + ((kc * 4 + quad) ^ (l15 & 7)) * 8];
                oacc_l[band] = __builtin_amdgcn_mfma_f32_16x16x32_bf16(
                    vf1, pf[kc], oacc_l[band], 0, 0, 0);
            }
        }
    }

    // normalize + store: l for q-col l15 lives at lane l15 (quad 0), reg 0
    #pragma unroll
    for (int band = 0; band < 2; ++band) {
        float l_val = __shfl(oacc_l[band][0], l15);
        float inv = 1.f / l_val;
        int row = q0 + band * 64 + 16 * w + l15;
        if (row < SS) {
            #pragma unroll
            for (int nf2 = 0; nf2 < 4; ++nf2)
                *(ushort4*)&o[obase + (size_t)row * HH + nf2 * 16 + quad * 4] =
                    pack4_bf16(oacc[band][nf2][0] * inv, oacc[band][nf2][1] * inv,
                               oacc[band][nf2][2] * inv, oacc[band][nf2][3] * inv);
        }
    }
}

// ======================= Classifier: grid (16 n-chunks, B) =======================
__global__ __launch_bounds__(256) void cls_kernel(
    const float* __restrict__ h, const float* __restrict__ wc,
    const float* __restrict__ bc, float* __restrict__ out)
{
    __shared__ float hr[HH];
    __shared__ float part[4][64];
    int b = blockIdx.y, n0 = blockIdx.x * 64;
    int t = threadIdx.x;
    for (int i = t; i < HH; i += 256) hr[i] = h[(size_t)b * SS * HH + i];
    __syncthreads();
    int nn = t & 63, seg = t >> 6;
    int n = n0 + nn;
    float acc = 0.f;
    if (n < NC) {
        #pragma unroll 4
        for (int kk = seg * 96; kk < seg * 96 + 96; ++kk)
            acc += hr[kk] * wc[(size_t)kk * NC + n];
    }
    part[seg][nn] = acc;
    __syncthreads();
    if (t < 64 && n0 + t < NC)
        out[b * NC + n0 + t] = part[0][t] + part[1][t] + part[2][t] + part[3][t] + bc[n0 + t];
}

// ======================= Launch =======================
extern "C" void kernel_launch(void* const* d_in, const int* in_sizes, int n_in,
                              void* d_out, int out_size, void* d_ws, size_t ws_size,
                              hipStream_t stream) {
    const float* x        = (const float*)d_in[0];
    const float* conv_w   = (const float*)d_in[1];
    const float* conv_b   = (const float*)d_in[2];
    const float* cls_tok  = (const float*)d_in[3];
    const float* pos_emb  = (const float*)d_in[4];
    const float* ln1_w    = (const float*)d_in[5];
    const float* ln1_b    = (const float*)d_in[6];
    const float* wq       = (const float*)d_in[7];
    const float* bq       = (const float*)d_in[8];
    const float* wk       = (const float*)d_in[9];
    const float* bk       = (const float*)d_in[10];
    const float* wv       = (const float*)d_in[11];
    const float* bv       = (const float*)d_in[12];
    const float* wo       = (const float*)d_in[13];
    const float* bo       = (const float*)d_in[14];
    const float* ln2_w    = (const float*)d_in[15];
    const float* ln2_b    = (const float*)d_in[16];
    const float* w1       = (const float*)d_in[17];
    const float* b1       = (const float*)d_in[18];
    const float* w2       = (const float*)d_in[19];
    const float* b2       = (const float*)d_in[20];
    const float* wc       = (const float*)d_in[21];
    const float* bc       = (const float*)d_in[22];
    float* out = (float*)d_out;

    char* wp = (char*)d_ws;
    float* h   = (float*)wp;  wp += (size_t)MROWS * HH * 4;          // 25.2 MB
    // hn and vtb share one region (disjoint lifetimes, stream-ordered)
    bf16* hn   = (bf16*)wp;
    bf16* vtb  = (bf16*)wp;   wp += (size_t)96 * DH * SSP * 2;       // 13.4 MB
    bf16* tb   = (bf16*)wp;   wp += (size_t)MPAD * HH * 2;           // 12.7 MB
    bf16* mb   = (bf16*)wp;   wp += (size_t)MPAD * II * 2;           // 50.7 MB
    bf16* qkvb = mb;          // qkv [MROWS][1152] aliases mb
    bf16* Pm   = mb;          // patch matrix aliases mb too
    bf16* wqkv = (bf16*)wp;   wp += (size_t)LL * QS * HH * 2;        // 10.6 MB
    bf16* wot  = (bf16*)wp;   wp += (size_t)LL * HH * HH * 2;        // 3.5 MB
    bf16* w1t  = (bf16*)wp;   wp += (size_t)LL * HH * II * 2;        // 14.2 MB
    bf16* w2t  = (bf16*)wp;   wp += (size_t)LL * II * HH * 2;        // 14.2 MB
    bf16* cwb  = (bf16*)wp;   wp += (size_t)HH * KPATCH * 2;         // 0.6 MB
    float* cbias = (float*)wp; wp += (size_t)LL * QS * 4;            // 55 KB

    // ---- weight prep ----
    transpose_cast_kernel<<<dim3(12, 12, LL), 256, 0, stream>>>(wq, wqkv,          HH, HH, QS * HH);
    transpose_cast_kernel<<<dim3(12, 12, LL), 256, 0, stream>>>(wk, wqkv + 147456, HH, HH, QS * HH);
    transpose_cast_kernel<<<dim3(12, 12, LL), 256, 0, stream>>>(wv, wqkv + 294912, HH, HH, QS * HH);
    transpose_cast_kernel<<<dim3(12, 12, LL), 256, 0, stream>>>(wo, wot, HH, HH, HH * HH);
    transpose_cast_kernel<<<dim3(48, 12, LL), 256, 0, stream>>>(w1, w1t, HH, II, HH * II);
    transpose_cast_kernel<<<dim3(12, 48, LL), 256, 0, stream>>>(w2, w2t, II, HH, II * HH);
    cast_kernel<<<288, 256, 0, stream>>>(conv_w, cwb, HH * KPATCH);
    bias_concat_kernel<<<LL, 384, 0, stream>>>(bq, bk, bv, cbias);

    // ---- patch embed as GEMM ----
    im2row_kernel<<<6144, 256, 0, stream>>>(x, Pm);
    gemm_v2_kernel<3><<<dim3(128, 3), 256, 0, stream>>>(
        Pm, cwb, conv_b, pos_emb, h, MPATCH, HH, KPATCH);
    fill_cls_kernel<<<BB, 384, 0, stream>>>(cls_tok, pos_emb, h);

    const int M = MROWS;
    dim3 gQKV(129, 9);   // N=1152
    dim3 gH(129, 3);     // N=384
    dim3 gI(129, 12);    // N=1536

    for (int l = 0; l < LL; ++l) {
        const float* l1w = ln1_w + (size_t)l * HH;
        const float* l1b = ln1_b + (size_t)l * HH;
        const float* l2w = ln2_w + (size_t)l * HH;
        const float* l2b = ln2_b + (size_t)l * HH;
        const bf16* wqkv_l = wqkv + (size_t)l * QS * HH;
        const bf16* wo_l   = wot  + (size_t)l * HH * HH;
        const bf16* w1_l   = w1t  + (size_t)l * HH * II;
        const bf16* w2_l   = w2t  + (size_t)l * II * HH;
        const float* cb_l  = cbias + (size_t)l * QS;
        const float* bo_l  = bo + (size_t)l * HH;
        const float* b1_l  = b1 + (size_t)l * II;
        const float* b2_l  = b2 + (size_t)l * HH;

        ln_kernel<<<4100, 256, 0, stream>>>(h, l1w, l1b, hn, M);

        gemm_v2_kernel<0><<<gQKV, 256, 0, stream>>>(hn, wqkv_l, cb_l, nullptr, qkvb, M, QS, HH);

        vt_kernel<<<dim3(33, 2, 96), 256, 0, stream>>>(qkvb, vtb);

        attn_v5_kernel<<<dim3(96, 9), 256, 0, stream>>>(qkvb, vtb, tb);

        gemm_v2_kernel<2><<<gH, 256, 0, stream>>>(tb, wo_l, bo_l, h, h, M, HH, HH);

        ln_kernel<<<4100, 256, 0, stream>>>(h, l2w, l2b, hn, M);

        gemm_v2_kernel<1><<<gI, 256, 0, stream>>>(hn, w1_l, b1_l, nullptr, mb, M, II, HH);
        gemm_v2_kernel<2><<<gH, 256, 0, stream>>>(mb, w2_l, b2_l, h, h, M, HH, II);
    }

    cls_kernel<<<dim3(16, BB), 256, 0, stream>>>(h, wc, bc, out);
}

// Round 7
// 3145.597 us; speedup vs baseline: 1.0803x; 1.0803x over previous
//
#include <hip/hip_runtime.h>
#include <hip/hip_bf16.h>
#include <math.h>

// ---- Model constants ----
#define BB 16
#define HH 384
#define NHEAD 6
#define DH 64
#define LL 12
#define II 1536
#define NC 1000
#define SS 1025
#define MROWS (BB * SS)      // 16400
#define MPAD  16512          // MROWS padded to multiple of 128
#define KPATCH 768           // 3*16*16
#define MPATCH (BB * 1024)   // 16384
#define QS 1152              // fused qkv row stride
#define SSP 1088             // padded seq stride for V^T (17*64)

typedef __hip_bfloat16 bf16;
typedef __attribute__((ext_vector_type(8))) short bh8;   // 8 bf16 (MFMA A/B frag)
typedef __attribute__((ext_vector_type(4))) float f4x;   // MFMA C/D frag

__device__ __forceinline__ void gload16(const bf16* g, bf16* l) {
    __builtin_amdgcn_global_load_lds(
        (const __attribute__((address_space(1))) unsigned int*)g,
        (__attribute__((address_space(3))) unsigned int*)l, 16, 0, 0);
}

__device__ __forceinline__ unsigned short bf16_bits(float f) {
    __hip_bfloat16 h = __float2bfloat16(f);
    return *reinterpret_cast<unsigned short*>(&h);
}
__device__ __forceinline__ ushort4 pack4_bf16(float a, float b, float c, float d) {
    ushort4 u;
    u.x = bf16_bits(a); u.y = bf16_bits(b); u.z = bf16_bits(c); u.w = bf16_bits(d);
    return u;
}

// ======================= transpose + cast: [L][K][N] f32 -> [L][N][K] bf16 =======================
__global__ __launch_bounds__(256) void transpose_cast_kernel(
    const float* __restrict__ in, bf16* __restrict__ out, int K, int N, int ostride)
{
    __shared__ float tile[32][33];
    int l = blockIdx.z;
    const float* ip = in + (size_t)l * K * N;
    bf16* op = out + (size_t)l * ostride;
    int n0 = blockIdx.x * 32, k0 = blockIdx.y * 32;
    int tx = threadIdx.x & 31, ty = threadIdx.x >> 5;   // 32 x 8
    #pragma unroll
    for (int i = 0; i < 32; i += 8)
        tile[ty + i][tx] = ip[(size_t)(k0 + ty + i) * N + n0 + tx];
    __syncthreads();
    #pragma unroll
    for (int i = 0; i < 32; i += 8)
        op[(size_t)(n0 + ty + i) * K + k0 + tx] = __float2bfloat16(tile[tx][ty + i]);
}

// ======================= plain cast f32 -> bf16 =======================
__global__ __launch_bounds__(256) void cast_kernel(
    const float* __restrict__ in, bf16* __restrict__ out, int n)
{
    int i = blockIdx.x * 1024 + threadIdx.x * 4;
    if (i + 3 < n) {
        float4 v = *(const float4*)&in[i];
        out[i]   = __float2bfloat16(v.x);
        out[i+1] = __float2bfloat16(v.y);
        out[i+2] = __float2bfloat16(v.z);
        out[i+3] = __float2bfloat16(v.w);
    } else {
        for (int j = i; j < n; ++j) out[j] = __float2bfloat16(in[j]);
    }
}

// ======================= concat qkv biases: cb[l][1152] =======================
__global__ __launch_bounds__(384) void bias_concat_kernel(
    const float* __restrict__ bq, const float* __restrict__ bk,
    const float* __restrict__ bv, float* __restrict__ cb)
{
    int l = blockIdx.x, t = threadIdx.x;
    cb[l * QS + t]       = bq[l * HH + t];
    cb[l * QS + 384 + t] = bk[l * HH + t];
    cb[l * QS + 768 + t] = bv[l * HH + t];
}

// ======================= im2row: x[B,3,512,512] -> Pm[16384][768] bf16 =======================
__global__ __launch_bounds__(256) void im2row_kernel(
    const float* __restrict__ x, bf16* __restrict__ Pm)
{
    size_t idx = ((size_t)blockIdx.x * 256 + threadIdx.x) * 8;
    int kk = (int)(idx % KPATCH);
    int m  = (int)(idx / KPATCH);
    int b = m >> 10, p = m & 1023;
    int c = kk >> 8, rem = kk & 255, py = rem >> 4, px = rem & 15;
    int pi = p >> 5, pj = p & 31;
    const float* src = &x[(((size_t)b * 3 + c) * 512 + pi * 16 + py) * 512 + pj * 16 + px];
    float4 a0 = *(const float4*)src;
    float4 a1 = *(const float4*)(src + 4);
    bf16 tmp[8];
    tmp[0] = __float2bfloat16(a0.x); tmp[1] = __float2bfloat16(a0.y);
    tmp[2] = __float2bfloat16(a0.z); tmp[3] = __float2bfloat16(a0.w);
    tmp[4] = __float2bfloat16(a1.x); tmp[5] = __float2bfloat16(a1.y);
    tmp[6] = __float2bfloat16(a1.z); tmp[7] = __float2bfloat16(a1.w);
    *(bh8*)&Pm[idx] = *(bh8*)tmp;
}

// ======================= fill cls rows =======================
__global__ __launch_bounds__(384) void fill_cls_kernel(
    const float* __restrict__ cls, const float* __restrict__ pos, float* __restrict__ h)
{
    h[(size_t)blockIdx.x * SS * HH + threadIdx.x] = cls[threadIdx.x] + pos[threadIdx.x];
}

// ======================= LayerNorm (fp32 in -> bf16 out) =======================
__global__ __launch_bounds__(256) void ln_kernel(
    const float* __restrict__ x, const float* __restrict__ w,
    const float* __restrict__ b, bf16* __restrict__ out, int nrows)
{
    int wave = threadIdx.x >> 6;
    int lane = threadIdx.x & 63;
    int row = blockIdx.x * 4 + wave;
    if (row >= nrows) return;
    const float* xr = x + (size_t)row * HH;
    float vals[6];
    float s = 0.f;
    #pragma unroll
    for (int i = 0; i < 6; ++i) { vals[i] = xr[lane + 64 * i]; s += vals[i]; }
    #pragma unroll
    for (int mask = 32; mask >= 1; mask >>= 1) s += __shfl_xor(s, mask);
    float mean = s * (1.f / HH);
    float vs = 0.f;
    #pragma unroll
    for (int i = 0; i < 6; ++i) { float d = vals[i] - mean; vs += d * d; }
    #pragma unroll
    for (int mask = 32; mask >= 1; mask >>= 1) vs += __shfl_xor(vs, mask);
    float rstd = rsqrtf(vs * (1.f / HH) + 1e-5f);
    bf16* outr = out + (size_t)row * HH;
    #pragma unroll
    for (int i = 0; i < 6; ++i) {
        int jj = lane + 64 * i;
        outr[jj] = __float2bfloat16((vals[i] - mean) * rstd * w[jj] + b[jj]);
    }
}

// ======================= MFMA GEMM (C^T accum, vectorized epilogue) =======================
// A[M][K]bf16 x Bt[N][K]bf16; 128x128 tile, GBK=64, global_load_lds + XOR swizzle.
// MODE 1: out bf16 = gelu(acc + bias)
// MODE 2: out f32  = acc + bias + res[row*N+col]
// MODE 3: patch embed scatter: h[b*SS+1+p][col] = acc + bias + pos[(1+p)*HH+col]
// MODE 4: out bf16 = acc + bias (qkv); v-section cols also scattered to vtout[bh][d][s]
template<int MODE>
__global__ __launch_bounds__(256) void gemm_v2_kernel(
    const bf16* __restrict__ A, const bf16* __restrict__ Bt,
    const float* __restrict__ bias, const float* __restrict__ res,
    void* __restrict__ out, bf16* __restrict__ vtout, int M, int N, int K)
{
    __shared__ bf16 As[128 * 64];
    __shared__ bf16 Bs[128 * 64];

    int t = threadIdx.x;
    int w = t >> 6, lane = t & 63;
    int quad = lane >> 4, l15 = lane & 15;
    int bm = blockIdx.x * 128, bn = blockIdx.y * 128;
    int wm = (w >> 1) * 64, wn = (w & 1) * 64;

    int srow = lane >> 3;
    int scol = lane & 7;

    f4x acc[4][4];
    #pragma unroll
    for (int i = 0; i < 4; ++i)
        #pragma unroll
        for (int j = 0; j < 4; ++j) acc[i][j] = 0.f;

    for (int k0 = 0; k0 < K; k0 += 64) {
        #pragma unroll
        for (int p = 0; p < 4; ++p) {
            int c = w * 4 + p;
            int r = c * 8 + srow;
            int gcb = scol ^ (r & 7);
            gload16(A + (size_t)(bm + r) * K + k0 + gcb * 8, &As[c * 8 * 64]);
        }
        #pragma unroll
        for (int p = 0; p < 4; ++p) {
            int c = w * 4 + p;
            int r = c * 8 + srow;
            int gcb = scol ^ (r & 7);
            gload16(Bt + (size_t)(bn + r) * K + k0 + gcb * 8, &Bs[c * 8 * 64]);
        }
        __syncthreads();

        #pragma unroll
        for (int kc = 0; kc < 2; ++kc) {
            bh8 bfr[4];
            #pragma unroll
            for (int nf = 0; nf < 4; ++nf) {
                int rn = wn + nf * 16 + l15;
                int pcb = (kc * 4 + quad) ^ (rn & 7);
                bfr[nf] = *(const bh8*)&Bs[rn * 64 + pcb * 8];
            }
            #pragma unroll
            for (int mf = 0; mf < 4; ++mf) {
                int rm = wm + mf * 16 + l15;
                int pcb = (kc * 4 + quad) ^ (rm & 7);
                bh8 afr = *(const bh8*)&As[rm * 64 + pcb * 8];
                #pragma unroll
                for (int nf = 0; nf < 4; ++nf)
                    acc[mf][nf] = __builtin_amdgcn_mfma_f32_16x16x32_bf16(
                        bfr[nf], afr, acc[mf][nf], 0, 0, 0);
            }
        }
        __syncthreads();
    }

    #pragma unroll
    for (int mf = 0; mf < 4; ++mf) {
        int row = bm + wm + mf * 16 + l15;
        #pragma unroll
        for (int nf = 0; nf < 4; ++nf) {
            f4x v = acc[mf][nf];
            int col0 = bn + wn + nf * 16 + quad * 4;
            float4 b4 = *(const float4*)&bias[col0];
            float vals[4];
            #pragma unroll
            for (int r = 0; r < 4; ++r) vals[r] = v[r] + (&b4.x)[r];
            if (MODE == 1) {
                #pragma unroll
                for (int r = 0; r < 4; ++r) {
                    float u = vals[r];
                    float z = 0.7978845608028654f * (u + 0.044715f * u * u * u);
                    z = fminf(fmaxf(z, -15.f), 15.f);
                    float e = __expf(2.f * z);
                    vals[r] = 0.5f * u * (1.f + (e - 1.f) / (e + 1.f));
                }
                if (row < M)
                    *(ushort4*)&((bf16*)out)[(size_t)row * N + col0] =
                        pack4_bf16(vals[0], vals[1], vals[2], vals[3]);
            } else if (MODE == 2) {
                if (row < M) {
                    float* o = (float*)out;
                    float4 r4 = *(const float4*)&res[(size_t)row * N + col0];
                    float4 st = {vals[0] + r4.x, vals[1] + r4.y,
                                 vals[2] + r4.z, vals[3] + r4.w};
                    *(float4*)&o[(size_t)row * N + col0] = st;
                }
            } else if (MODE == 3) {
                int b2 = row >> 10, p2 = row & 1023;
                size_t orow = (size_t)b2 * SS + 1 + p2;
                float4 r4 = *(const float4*)&res[(size_t)(1 + p2) * HH + col0];
                float4 st = {vals[0] + r4.x, vals[1] + r4.y,
                             vals[2] + r4.z, vals[3] + r4.w};
                *(float4*)&((float*)out)[orow * HH + col0] = st;
            } else {  // MODE 4: qkv write + fused V^T scatter
                if (row < M) {
                    *(ushort4*)&((bf16*)out)[(size_t)row * N + col0] =
                        pack4_bf16(vals[0], vals[1], vals[2], vals[3]);
                    if (col0 >= 768) {
                        int b2 = row / 1025;            // magic-mul div
                        int s  = row - b2 * 1025;
                        int dg = col0 - 768;
                        int hd2 = dg >> 6, dd = dg & 63;
                        bf16* vp = vtout +
                            ((size_t)((b2 * NHEAD + hd2) * DH + dd)) * SSP + s;
                        vp[0]       = __float2bfloat16(vals[0]);
                        vp[SSP]     = __float2bfloat16(vals[1]);
                        vp[2 * SSP] = __float2bfloat16(vals[2]);
                        vp[3 * SSP] = __float2bfloat16(vals[3]);
                    }
                }
            }
        }
    }
}

// ======================= Fused MFMA attention v6 =======================
// v4 math (64 q-rows/block, fixed-shift exp2 softmax, transposed MFMAs) +
// double-buffered K/V staging with ONE barrier per key-tile: the vmcnt drain
// at each barrier waits on loads issued a full compute-phase earlier.
// grid (96, 17): bh fastest for L2 K/V reuse. block 256.
#define PSTR 68   // Ps row stride (elems)

__global__ __launch_bounds__(256) void attn_v6_kernel(
    const bf16* __restrict__ qkv, const bf16* __restrict__ vt,
    bf16* __restrict__ o)
{
    __shared__ bf16 Qs[64 * 64];
    __shared__ bf16 Ks[2][64 * 64];
    __shared__ bf16 Vs[2][64 * 64];
    __shared__ bf16 Ps[4][16 * PSTR];

    int t = threadIdx.x, w = t >> 6, lane = t & 63;
    int quad = lane >> 4, l15 = lane & 15;
    int bh = blockIdx.x;
    int b = bh / NHEAD, hd = bh % NHEAD;
    int q0 = blockIdx.y * 64;
    size_t qbase = ((size_t)b * SS) * QS + hd * DH;
    size_t kbase = qbase + 384;
    size_t vbase = (size_t)bh * DH * SSP;
    size_t obase = ((size_t)b * SS) * HH + hd * DH;

    int srow = lane >> 3, scol = lane & 7;
    int gcb = scol ^ srow;

    // prologue: stage Q tile + first K/V tile into buf 0
    #pragma unroll
    for (int p = 0; p < 2; ++p) {
        int c = w * 2 + p;
        int r = c * 8 + srow;
        gload16(qkv + qbase + (size_t)(q0 + r) * QS + gcb * 8, &Qs[c * 512]);
        gload16(qkv + kbase + (size_t)r * QS + gcb * 8, &Ks[0][c * 512]);
        gload16(vt + vbase + (size_t)r * SSP + gcb * 8, &Vs[0][c * 512]);
    }
    __syncthreads();

    bh8 qfrag[2];
    {
        int rm = 16 * w + l15;
        #pragma unroll
        for (int kc = 0; kc < 2; ++kc)
            qfrag[kc] = *(const bh8*)&Qs[rm * 64 + ((kc * 4 + quad) ^ (rm & 7)) * 8];
    }

    f4x oacc[4];
    #pragma unroll
    for (int i = 0; i < 4; ++i) oacc[i] = 0.f;
    float l_part = 0.f;

    const float C1 = 0.18033688011112042f;  // 0.125 * log2(e)
    const float C2 = -16.0f;                // fixed shift (cancels in normalize)

    const int NT = (SS + 63) / 64;          // 17
    for (int it = 0; it < NT; ++it) {
        int cur = it & 1;
        int c0 = it * 64;

        // prefetch next tile into the other buffer (latency hidden by compute)
        if (it + 1 < NT) {
            int nxt = cur ^ 1;
            int c1 = c0 + 64;
            #pragma unroll
            for (int p = 0; p < 2; ++p) {
                int c = w * 2 + p;
                int r = c * 8 + srow;
                gload16(qkv + kbase + (size_t)(c1 + r) * QS + gcb * 8, &Ks[nxt][c * 512]);
                gload16(vt + vbase + (size_t)r * SSP + c1 + gcb * 8, &Vs[nxt][c * 512]);
            }
        }

        bool tail = (c0 + 64 > SS);   // wave-uniform
        // S^T = mfma(K, Q^T); P = exp2(S*C1 + C2)
        #pragma unroll
        for (int nf = 0; nf < 4; ++nf) {
            f4x s = 0.f;
            int rn = nf * 16 + l15;
            #pragma unroll
            for (int kc = 0; kc < 2; ++kc) {
                bh8 kf = *(const bh8*)&Ks[cur][rn * 64 + ((kc * 4 + quad) ^ (rn & 7)) * 8];
                s = __builtin_amdgcn_mfma_f32_16x16x32_bf16(kf, qfrag[kc], s, 0, 0, 0);
            }
            float pv[4];
            if (tail) {
                #pragma unroll
                for (int r = 0; r < 4; ++r) {
                    float p = exp2f(fmaf(s[r], C1, C2));
                    pv[r] = (c0 + nf * 16 + quad * 4 + r < SS) ? p : 0.f;
                }
            } else {
                #pragma unroll
                for (int r = 0; r < 4; ++r)
                    pv[r] = exp2f(fmaf(s[r], C1, C2));
            }
            #pragma unroll
            for (int r = 0; r < 4; ++r) l_part += pv[r];
            *(ushort4*)&Ps[w][l15 * PSTR + nf * 16 + quad * 4] =
                pack4_bf16(pv[0], pv[1], pv[2], pv[3]);
        }

        // wave-private P^T read (B-frag)
        bh8 pf[2];
        #pragma unroll
        for (int kc = 0; kc < 2; ++kc)
            pf[kc] = *(const bh8*)&Ps[w][l15 * PSTR + kc * 32 + quad * 8];

        // O^T += V^T * P^T
        #pragma unroll
        for (int nf2 = 0; nf2 < 4; ++nf2) {
            int rn2 = nf2 * 16 + l15;
            #pragma unroll
            for (int kc = 0; kc < 2; ++kc) {
                bh8 vf = *(const bh8*)&Vs[cur][rn2 * 64 + ((kc * 4 + quad) ^ (rn2 & 7)) * 8];
                oacc[nf2] = __builtin_amdgcn_mfma_f32_16x16x32_bf16(vf, pf[kc], oacc[nf2], 0, 0, 0);
            }
        }

        __syncthreads();   // drains prefetch (issued pre-compute) + guards buffer reuse
    }

    // reduce l across the 4 quads sharing this q-column
    l_part += __shfl_xor(l_part, 16);
    l_part += __shfl_xor(l_part, 32);
    float inv = 1.f / l_part;

    int row = q0 + 16 * w + l15;
    if (row < SS) {
        #pragma unroll
        for (int nf2 = 0; nf2 < 4; ++nf2)
            *(ushort4*)&o[obase + (size_t)row * HH + nf2 * 16 + quad * 4] =
                pack4_bf16(oacc[nf2][0] * inv, oacc[nf2][1] * inv,
                           oacc[nf2][2] * inv, oacc[nf2][3] * inv);
    }
}

// ======================= Classifier: grid (16 n-chunks, B) =======================
__global__ __launch_bounds__(256) void cls_kernel(
    const float* __restrict__ h, const float* __restrict__ wc,
    const float* __restrict__ bc, float* __restrict__ out)
{
    __shared__ float hr[HH];
    __shared__ float part[4][64];
    int b = blockIdx.y, n0 = blockIdx.x * 64;
    int t = threadIdx.x;
    for (int i = t; i < HH; i += 256) hr[i] = h[(size_t)b * SS * HH + i];
    __syncthreads();
    int nn = t & 63, seg = t >> 6;
    int n = n0 + nn;
    float acc = 0.f;
    if (n < NC) {
        #pragma unroll 4
        for (int kk = seg * 96; kk < seg * 96 + 96; ++kk)
            acc += hr[kk] * wc[(size_t)kk * NC + n];
    }
    part[seg][nn] = acc;
    __syncthreads();
    if (t < 64 && n0 + t < NC)
        out[b * NC + n0 + t] = part[0][t] + part[1][t] + part[2][t] + part[3][t] + bc[n0 + t];
}

// ======================= Launch =======================
extern "C" void kernel_launch(void* const* d_in, const int* in_sizes, int n_in,
                              void* d_out, int out_size, void* d_ws, size_t ws_size,
                              hipStream_t stream) {
    const float* x        = (const float*)d_in[0];
    const float* conv_w   = (const float*)d_in[1];
    const float* conv_b   = (const float*)d_in[2];
    const float* cls_tok  = (const float*)d_in[3];
    const float* pos_emb  = (const float*)d_in[4];
    const float* ln1_w    = (const float*)d_in[5];
    const float* ln1_b    = (const float*)d_in[6];
    const float* wq       = (const float*)d_in[7];
    const float* bq       = (const float*)d_in[8];
    const float* wk       = (const float*)d_in[9];
    const float* bk       = (const float*)d_in[10];
    const float* wv       = (const float*)d_in[11];
    const float* bv       = (const float*)d_in[12];
    const float* wo       = (const float*)d_in[13];
    const float* bo       = (const float*)d_in[14];
    const float* ln2_w    = (const float*)d_in[15];
    const float* ln2_b    = (const float*)d_in[16];
    const float* w1       = (const float*)d_in[17];
    const float* b1       = (const float*)d_in[18];
    const float* w2       = (const float*)d_in[19];
    const float* b2       = (const float*)d_in[20];
    const float* wc       = (const float*)d_in[21];
    const float* bc       = (const float*)d_in[22];
    float* out = (float*)d_out;

    char* wp = (char*)d_ws;
    float* h   = (float*)wp;  wp += (size_t)MROWS * HH * 4;          // 25.2 MB
    bf16* hn   = (bf16*)wp;   wp += (size_t)MPAD * HH * 2;           // 12.7 MB
    bf16* vtb  = (bf16*)wp;   wp += (size_t)96 * DH * SSP * 2;       // 13.4 MB (own region: fused writes)
    bf16* tb   = (bf16*)wp;   wp += (size_t)MPAD * HH * 2;           // 12.7 MB
    bf16* mb   = (bf16*)wp;   wp += (size_t)MPAD * II * 2;           // 50.7 MB
    bf16* qkvb = mb;          // qkv [MROWS][1152] aliases mb
    bf16* Pm   = mb;          // patch matrix aliases mb too
    bf16* wqkv = (bf16*)wp;   wp += (size_t)LL * QS * HH * 2;        // 10.6 MB
    bf16* wot  = (bf16*)wp;   wp += (size_t)LL * HH * HH * 2;        // 3.5 MB
    bf16* w1t  = (bf16*)wp;   wp += (size_t)LL * HH * II * 2;        // 14.2 MB
    bf16* w2t  = (bf16*)wp;   wp += (size_t)LL * II * HH * 2;        // 14.2 MB
    bf16* cwb  = (bf16*)wp;   wp += (size_t)HH * KPATCH * 2;         // 0.6 MB
    float* cbias = (float*)wp; wp += (size_t)LL * QS * 4;            // 55 KB

    // ---- weight prep ----
    transpose_cast_kernel<<<dim3(12, 12, LL), 256, 0, stream>>>(wq, wqkv,          HH, HH, QS * HH);
    transpose_cast_kernel<<<dim3(12, 12, LL), 256, 0, stream>>>(wk, wqkv + 147456, HH, HH, QS * HH);
    transpose_cast_kernel<<<dim3(12, 12, LL), 256, 0, stream>>>(wv, wqkv + 294912, HH, HH, QS * HH);
    transpose_cast_kernel<<<dim3(12, 12, LL), 256, 0, stream>>>(wo, wot, HH, HH, HH * HH);
    transpose_cast_kernel<<<dim3(48, 12, LL), 256, 0, stream>>>(w1, w1t, HH, II, HH * II);
    transpose_cast_kernel<<<dim3(12, 48, LL), 256, 0, stream>>>(w2, w2t, II, HH, II * HH);
    cast_kernel<<<288, 256, 0, stream>>>(conv_w, cwb, HH * KPATCH);
    bias_concat_kernel<<<LL, 384, 0, stream>>>(bq, bk, bv, cbias);

    // ---- patch embed as GEMM ----
    im2row_kernel<<<6144, 256, 0, stream>>>(x, Pm);
    gemm_v2_kernel<3><<<dim3(128, 3), 256, 0, stream>>>(
        Pm, cwb, conv_b, pos_emb, h, nullptr, MPATCH, HH, KPATCH);
    fill_cls_kernel<<<BB, 384, 0, stream>>>(cls_tok, pos_emb, h);

    const int M = MROWS;
    dim3 gQKV(129, 9);   // N=1152
    dim3 gH(129, 3);     // N=384
    dim3 gI(129, 12);    // N=1536

    for (int l = 0; l < LL; ++l) {
        const float* l1w = ln1_w + (size_t)l * HH;
        const float* l1b = ln1_b + (size_t)l * HH;
        const float* l2w = ln2_w + (size_t)l * HH;
        const float* l2b = ln2_b + (size_t)l * HH;
        const bf16* wqkv_l = wqkv + (size_t)l * QS * HH;
        const bf16* wo_l   = wot  + (size_t)l * HH * HH;
        const bf16* w1_l   = w1t  + (size_t)l * HH * II;
        const bf16* w2_l   = w2t  + (size_t)l * II * HH;
        const float* cb_l  = cbias + (size_t)l * QS;
        const float* bo_l  = bo + (size_t)l * HH;
        const float* b1_l  = b1 + (size_t)l * II;
        const float* b2_l  = b2 + (size_t)l * HH;

        ln_kernel<<<4100, 256, 0, stream>>>(h, l1w, l1b, hn, M);

        // QKV GEMM with fused V^T scatter
        gemm_v2_kernel<4><<<gQKV, 256, 0, stream>>>(hn, wqkv_l, cb_l, nullptr, qkvb, vtb, M, QS, HH);

        attn_v6_kernel<<<dim3(96, 17), 256, 0, stream>>>(qkvb, vtb, tb);

        gemm_v2_kernel<2><<<gH, 256, 0, stream>>>(tb, wo_l, bo_l, h, h, nullptr, M, HH, HH);

        ln_kernel<<<4100, 256, 0, stream>>>(h, l2w, l2b, hn, M);

        gemm_v2_kernel<1><<<gI, 256, 0, stream>>>(hn, w1_l, b1_l, nullptr, mb, nullptr, M, II, HH);
        gemm_v2_kernel<2><<<gH, 256, 0, stream>>>(mb, w2_l, b2_l, h, h, nullptr, M, HH, II);
    }

    cls_kernel<<<dim3(16, BB), 256, 0, stream>>>(h, wc, bc, out);
}